// Round 2
// baseline (507.641 us; speedup 1.0000x reference)
//
#include <hip/hip_runtime.h>
#include <stdint.h>

// Problem constants
#define D_DIM   1024
#define NTOK    4096      // G*S
#define NROUTE  8192      // NTOK * K(=2)
#define E_NUM   16
#define ESLOT   17        // 16 routed + 1 shared
#define MAXROWS 14336     // max padded entry rows: <=10240 routed + 4096 shared
#define BM      128
#define BN      128
#define MAXTILES 112      // MAXROWS / BM

typedef __attribute__((ext_vector_type(8))) short bf16x8;   // 8 bf16 (4 VGPRs)
typedef __attribute__((ext_vector_type(8))) unsigned short u16x8;
typedef __attribute__((ext_vector_type(4))) float f32x4;

static __device__ __forceinline__ unsigned short f2b(float f) {  // fp32 -> bf16 RNE
  unsigned u = __builtin_bit_cast(unsigned, f);
  u += 0x7fffu + ((u >> 16) & 1u);
  return (unsigned short)(u >> 16);
}
static __device__ __forceinline__ float b2f(unsigned short h) {
  unsigned u = ((unsigned)h) << 16;
  return __builtin_bit_cast(float, u);
}

// CK-style async global->LDS, 16B per lane. dest = M0(wave-uniform) + lane*16.
static __device__ __forceinline__ void gload_lds16(const void* src, void* lds) {
  unsigned m0v = __builtin_amdgcn_readfirstlane((unsigned)(uintptr_t)lds);
  asm volatile("s_mov_b32 m0, %0\n\t"
               "global_load_lds_dwordx4 %1, off"
               :: "s"(m0v), "v"(src) : "memory");
}

// ---------------- x fp32 -> bf16 (+ zero entry-token array) ----------------
__global__ void k_convert_x(const float* __restrict__ x, unsigned short* __restrict__ xb,
                            int* __restrict__ etok) {
  long gid = (long)blockIdx.x * 256 + threadIdx.x;
  if (gid < MAXROWS) etok[gid] = 0;   // padding entries -> token 0 (safe row)
  long i = gid * 4;
  float4 v = *(const float4*)(x + i);
  ushort4 o = make_ushort4(f2b(v.x), f2b(v.y), f2b(v.z), f2b(v.w));
  *(ushort4*)(xb + i) = o;
}

// ---------------- weights fp32 [K][N] -> bf16 transposed [N][K] ----------------
// Wt1[e] = [Wg^T | Wu^T] : [2048][1024];  Wt2[e] = Wd^T : [1024][1024]
__global__ void k_trans_w(const float* __restrict__ Wg, const float* __restrict__ Wu,
                          const float* __restrict__ Wd, const float* __restrict__ sg,
                          const float* __restrict__ su, const float* __restrict__ sd,
                          unsigned short* __restrict__ Wt1, unsigned short* __restrict__ Wt2) {
  int bid = blockIdx.x;
  int slot = bid >> 8;          // 0..50  (= m*17+e)
  int tilei = bid & 255;        // 16x16 tiles of 64x64
  int kt = (tilei >> 4) * 64;
  int nt = (tilei & 15) * 64;
  int m = slot / ESLOT, e = slot % ESLOT;
  const float* src;
  if (e < E_NUM) src = (m == 0 ? Wg : m == 1 ? Wu : Wd) + (size_t)e * (D_DIM * D_DIM);
  else           src = (m == 0 ? sg : m == 1 ? su : sd);
  unsigned short* dst;
  if (m < 2) dst = Wt1 + (size_t)e * (2048 * 1024) + (size_t)m * (1024 * 1024);
  else       dst = Wt2 + (size_t)e * (1024 * 1024);

  __shared__ float tile[64][65];   // +1 pad: conflict-free column reads
  int tid = threadIdx.x;
#pragma unroll
  for (int it = 0; it < 4; it++) {
    int flat = it * 1024 + tid * 4;
    int r = flat >> 6, c = flat & 63;
    float4 v = *(const float4*)&src[(size_t)(kt + r) * D_DIM + nt + c];
    tile[r][c] = v.x; tile[r][c + 1] = v.y; tile[r][c + 2] = v.z; tile[r][c + 3] = v.w;
  }
  __syncthreads();
#pragma unroll
  for (int it = 0; it < 2; it++) {
    int flat = it * 2048 + tid * 8;   // element index in 64x64 tile, [n][k] order
    int n = flat >> 6, k = flat & 63;
    u16x8 o;
#pragma unroll
    for (int j = 0; j < 8; j++) o[j] = f2b(tile[k + j][n]);
    *(u16x8*)&dst[(size_t)(nt + n) * D_DIM + kt + k] = o;
  }
}

// ---------------- routing dispatch (1 block) ----------------
__global__ void k_dispatch(const int* __restrict__ idx,
                           int* __restrict__ etok, int* __restrict__ pos2,
                           int* __restrict__ ebase, int* __restrict__ tile_e,
                           int* __restrict__ tile_r, int* __restrict__ ntp) {
  __shared__ int cnt[ESLOT];
  __shared__ int cur[E_NUM];
  __shared__ int basz[ESLOT + 1];
  int tid = threadIdx.x;  // 256
  if (tid < ESLOT) cnt[tid] = 0;
  __syncthreads();
  for (int i = tid; i < NROUTE; i += 256) atomicAdd(&cnt[idx[i]], 1);
  __syncthreads();
  if (tid == 0) {
    int off = 0;
    for (int e = 0; e < E_NUM; e++) { basz[e] = off; off += ((cnt[e] + BM - 1) / BM) * BM; }
    basz[E_NUM] = off;                 // shared expert segment (4096, already x128)
    basz[E_NUM + 1] = off + NTOK;
    int t = 0;
    for (int e = 0; e <= E_NUM; e++) {
      int c = (e == E_NUM) ? NTOK : cnt[e];
      for (int r = 0; r < c; r += BM) { tile_e[t] = e; tile_r[t] = basz[e] + r; t++; }
    }
    *ntp = t;                          // <= 112
  }
  if (tid < E_NUM) cur[tid] = 0;
  __syncthreads();
  for (int i = tid; i < NROUTE; i += 256) {
    int e = idx[i];
    int p = basz[e] + atomicAdd(&cur[e], 1);
    etok[p] = i >> 1;                  // token id (K=2)
    pos2[i] = p;                       // where (token,k)'s y lands
  }
  for (int i = tid; i < NTOK; i += 256) etok[basz[E_NUM] + i] = i;
  if (tid < ESLOT + 1) ebase[tid] = basz[tid];
}

// ---------------- grouped GEMM, m97 structure: 128x128 tile, 4 waves, 4x4 frags ----
// LDS sub-tiled [kq][row][8] so staging (linear lane order) AND frag ds_read_b128
// are both quarter-wave-contiguous (0 bank conflicts, measured).
template <bool GATHER>
__device__ __forceinline__ void gemm_body(
    const unsigned short* __restrict__ Abase, int lda,
    const unsigned short* __restrict__ Wslot, size_t slot_stride,
    const int* __restrict__ etok,
    const int* __restrict__ tile_e, const int* __restrict__ tile_r,
    const int* __restrict__ ntp,
    unsigned short* __restrict__ Out, int ldo) {
  int bt = blockIdx.y;
  if (bt >= *ntp) return;
  int e = tile_e[bt];
  int row0 = tile_r[bt];
  int n0 = blockIdx.x * BN;

  __shared__ __align__(16) unsigned short sA[4 * BM * 8];   // 8KB [kq][128][8]
  __shared__ __align__(16) unsigned short sB[4 * BN * 8];   // 8KB [kq][128][8]

  int tid = threadIdx.x;
  int wid = tid >> 6, lane = tid & 63;
  int wm = wid >> 1, wn = wid & 1;

  // staging: instr i covers slots i*256+tid; slot -> kq=slot>>7, row=slot&127
  int srow = tid & 127;
  int kq0 = tid >> 7;    // 0/1; instr1 covers kq0+2
  size_t arow = GATHER ? (size_t)etok[row0 + srow] : (size_t)(row0 + srow);
  const unsigned short* aptr = Abase + arow * (size_t)lda + kq0 * 8;
  const unsigned short* bptr = Wslot + (size_t)e * slot_stride
                               + (size_t)(n0 + srow) * D_DIM + kq0 * 8;

  char* sAb = (char*)sA; char* sBb = (char*)sB;
  int a_off[4], b_off[4];
#pragma unroll
  for (int f = 0; f < 4; f++) {
    a_off[f] = ((lane >> 4) * BM + wm * 64 + f * 16 + (lane & 15)) * 16;
    b_off[f] = ((lane >> 4) * BN + wn * 64 + f * 16 + (lane & 15)) * 16;
  }

  f32x4 acc[4][4] = {};

  for (int kk = 0; kk < D_DIM; kk += 32) {
    gload_lds16(aptr + kk,      sAb + wid * 1024);
    gload_lds16(aptr + kk + 16, sAb + 4096 + wid * 1024);
    gload_lds16(bptr + kk,      sBb + wid * 1024);
    gload_lds16(bptr + kk + 16, sBb + 4096 + wid * 1024);
    asm volatile("s_waitcnt vmcnt(0)" ::: "memory");
    __syncthreads();
    bf16x8 af[4], bfr[4];
#pragma unroll
    for (int f = 0; f < 4; f++) {
      af[f]  = *(const bf16x8*)(sAb + a_off[f]);
      bfr[f] = *(const bf16x8*)(sBb + b_off[f]);
    }
#pragma unroll
    for (int i = 0; i < 4; i++)
#pragma unroll
      for (int j = 0; j < 4; j++)
        acc[i][j] = __builtin_amdgcn_mfma_f32_16x16x32_bf16(af[i], bfr[j], acc[i][j], 0, 0, 0);
    __syncthreads();
  }

  // C/D layout: col=lane&15, row=(lane>>4)*4+q (m89/m91 verified)
  int crow = row0 + wm * 64 + (lane >> 4) * 4;
  int ccol = n0 + wn * 64 + (lane & 15);
#pragma unroll
  for (int i = 0; i < 4; i++)
#pragma unroll
    for (int j = 0; j < 4; j++)
#pragma unroll
      for (int q = 0; q < 4; q++)
        Out[(size_t)(crow + i * 16 + q) * ldo + ccol + j * 16] = f2b(acc[i][j][q]);
}

__global__ void __launch_bounds__(256)
k_gemm_gu(const unsigned short* __restrict__ xb, const unsigned short* __restrict__ Wt1,
          const int* __restrict__ etok, const int* __restrict__ tile_e,
          const int* __restrict__ tile_r, const int* __restrict__ ntp,
          unsigned short* __restrict__ G) {
  gemm_body<true>(xb, 1024, Wt1, (size_t)2048 * 1024, etok, tile_e, tile_r, ntp, G, 2048);
}

__global__ void __launch_bounds__(256)
k_gemm_dn(const unsigned short* __restrict__ G, const unsigned short* __restrict__ Wt2,
          const int* __restrict__ tile_e, const int* __restrict__ tile_r,
          const int* __restrict__ ntp, unsigned short* __restrict__ Y) {
  // A = activated gate half of G (lda 2048); Y = up half of G (disjoint columns -> race-free)
  gemm_body<false>(G, 2048, Wt2, (size_t)1024 * 1024, nullptr, tile_e, tile_r, ntp, Y, 2048);
}

// ---------------- in-place activation: G[r][c] = silu(G[r][c]) * G[r][1024+c] ------
__global__ void k_act(unsigned short* __restrict__ G) {
  int gid = blockIdx.x * 256 + threadIdx.x;
  int r = gid >> 7;             // 128 threads per row
  int c = (gid & 127) * 8;
  unsigned short* p = G + (size_t)r * 2048 + c;
  u16x8 g = *(const u16x8*)p;
  u16x8 u = *(const u16x8*)(p + 1024);
  u16x8 o;
#pragma unroll
  for (int j = 0; j < 8; j++) {
    float gf = b2f(g[j]), uf = b2f(u[j]);
    float a = gf / (1.f + __expf(-gf)) * uf;
    o[j] = f2b(a);
  }
  *(u16x8*)p = o;
}

// ---------------- combine: out = w0*Y[p0] + w1*Y[p1] + Y[shared] ----------------
// Y lives at G + 1024 with row stride 2048
__global__ void k_combine(const unsigned short* __restrict__ Yb, const float* __restrict__ w,
                          const int* __restrict__ pos2, const int* __restrict__ ebase,
                          float* __restrict__ out) {
  int t = blockIdx.x;
  int tid = threadIdx.x;
  int p0 = pos2[t * 2], p1 = pos2[t * 2 + 1];
  float w0 = w[t * 2], w1 = w[t * 2 + 1];
  int ps = ebase[E_NUM] + t;
  int c = tid * 4;
  ushort4 ya = *(const ushort4*)(Yb + (size_t)p0 * 2048 + c);
  ushort4 yb = *(const ushort4*)(Yb + (size_t)p1 * 2048 + c);
  ushort4 ys = *(const ushort4*)(Yb + (size_t)ps * 2048 + c);
  float4 o;
  o.x = w0 * b2f(ya.x) + w1 * b2f(yb.x) + b2f(ys.x);
  o.y = w0 * b2f(ya.y) + w1 * b2f(yb.y) + b2f(ys.y);
  o.z = w0 * b2f(ya.z) + w1 * b2f(yb.z) + b2f(ys.z);
  o.w = w0 * b2f(ya.w) + w1 * b2f(yb.w) + b2f(ys.w);
  *(float4*)(out + (size_t)t * D_DIM + c) = o;
}

extern "C" void kernel_launch(void* const* d_in, const int* in_sizes, int n_in,
                              void* d_out, int out_size, void* d_ws, size_t ws_size,
                              hipStream_t stream) {
  (void)in_sizes; (void)n_in; (void)out_size; (void)ws_size;
  const float* x  = (const float*)d_in[0];
  const float* w  = (const float*)d_in[1];
  const int*   idx = (const int*)d_in[2];
  const float* Wg = (const float*)d_in[5];
  const float* Wu = (const float*)d_in[6];
  const float* Wd = (const float*)d_in[7];
  const float* sg = (const float*)d_in[8];
  const float* su = (const float*)d_in[9];
  const float* sd = (const float*)d_in[10];
  float* out = (float*)d_out;

  // workspace layout (bytes) -- total 174,155,012 (same as proven round 1)
  char* ws = (char*)d_ws;
  unsigned short* Wt1 = (unsigned short*)(ws + 0);            // 17*2048*1024*2 =  71,303,168
  unsigned short* Wt2 = (unsigned short*)(ws + 71303168);     // 17*1024*1024*2 =  35,651,584
  unsigned short* G   = (unsigned short*)(ws + 106954752);    // 14336*2048*2   =  58,720,256
  unsigned short* xb  = (unsigned short*)(ws + 165675008);    // 4096*1024*2    =   8,388,608
  int* etok   = (int*)(ws + 174063616);                       // 14336*4
  int* pos2   = (int*)(ws + 174120960);                       // 8192*4
  int* ebase  = (int*)(ws + 174153728);                       // 18*4 (pad 256)
  int* tile_e = (int*)(ws + 174153984);                       // 112*4 (pad 512)
  int* tile_r = (int*)(ws + 174154496);                       // 112*4 (pad 512)
  int* ntp    = (int*)(ws + 174155008);                       // 4

  k_convert_x<<<4096, 256, 0, stream>>>(x, xb, etok);
  k_trans_w<<<51 * 256, 256, 0, stream>>>(Wg, Wu, Wd, sg, su, sd, Wt1, Wt2);
  k_dispatch<<<1, 256, 0, stream>>>(idx, etok, pos2, ebase, tile_e, tile_r, ntp);
  k_gemm_gu<<<dim3(16, MAXTILES), 256, 0, stream>>>(xb, Wt1, etok, tile_e, tile_r, ntp, G);
  k_act<<<7168, 256, 0, stream>>>(G);
  k_gemm_dn<<<dim3(8, MAXTILES), 256, 0, stream>>>(G, Wt2, tile_e, tile_r, ntp, G + 1024);
  k_combine<<<NTOK, 256, 0, stream>>>(G + 1024, w, pos2, ebase, out);
}

// Round 3
// 476.036 us; speedup vs baseline: 1.0664x; 1.0664x over previous
//
#include <hip/hip_runtime.h>
#include <stdint.h>

// Problem constants
#define D_DIM   1024
#define NTOK    4096      // G*S
#define NROUTE  8192      // NTOK * K(=2)
#define E_NUM   16
#define ESLOT   17        // 16 routed + 1 shared
#define MAXROWS 14336     // max padded entry rows: <=10240 routed + 4096 shared
#define BM      128
#define BN      128
#define NT      32        // K-steps = D_DIM/32
#define MAXTILES 112      // MAXROWS / BM

typedef __attribute__((ext_vector_type(8))) short bf16x8;   // 8 bf16 (4 VGPRs)
typedef __attribute__((ext_vector_type(8))) unsigned short u16x8;
typedef __attribute__((ext_vector_type(4))) float f32x4;

static __device__ __forceinline__ unsigned short f2b(float f) {  // fp32 -> bf16 RNE
  unsigned u = __builtin_bit_cast(unsigned, f);
  u += 0x7fffu + ((u >> 16) & 1u);
  return (unsigned short)(u >> 16);
}
static __device__ __forceinline__ float b2f(unsigned short h) {
  unsigned u = ((unsigned)h) << 16;
  return __builtin_bit_cast(float, u);
}

// CK-style async global->LDS, 16B per lane. dest = M0(wave-uniform) + lane*16.
static __device__ __forceinline__ void gload_lds16(const void* src, void* lds) {
  unsigned m0v = __builtin_amdgcn_readfirstlane((unsigned)(uintptr_t)lds);
  asm volatile("s_mov_b32 m0, %0\n\t"
               "global_load_lds_dwordx4 %1, off"
               :: "s"(m0v), "v"(src) : "memory");
}

// ---------------- x fp32 -> bf16 (+ zero entry-token array) ----------------
__global__ void k_convert_x(const float* __restrict__ x, unsigned short* __restrict__ xb,
                            int* __restrict__ etok) {
  long gid = (long)blockIdx.x * 256 + threadIdx.x;
  if (gid < MAXROWS) etok[gid] = 0;   // padding entries -> token 0 (safe row)
  long i = gid * 4;
  float4 v = *(const float4*)(x + i);
  ushort4 o = make_ushort4(f2b(v.x), f2b(v.y), f2b(v.z), f2b(v.w));
  *(ushort4*)(xb + i) = o;
}

// ---------------- weights fp32 [K][N] -> bf16 transposed [N][K] ----------------
// Wt1[e]: 2048 physical rows; logical col n of matrix m (0=gate,1=up) at
// physical row (n>>4)*32 + m*16 + (n&15)  -> gate/up 16-col groups interleaved
// so one GEMM block (and one lane) holds matching gate/up pairs for the
// fused silu epilogue.  Wt2[e] = Wd^T plain [n][k].
__global__ void k_trans_w(const float* __restrict__ Wg, const float* __restrict__ Wu,
                          const float* __restrict__ Wd, const float* __restrict__ sg,
                          const float* __restrict__ su, const float* __restrict__ sd,
                          unsigned short* __restrict__ Wt1, unsigned short* __restrict__ Wt2) {
  int bid = blockIdx.x;
  int slot = bid >> 8;          // 0..50  (= m*17+e)
  int tilei = bid & 255;        // 16x16 tiles of 64x64
  int kt = (tilei >> 4) * 64;
  int nt = (tilei & 15) * 64;
  int m = slot / ESLOT, e = slot % ESLOT;
  const float* src;
  if (e < E_NUM) src = (m == 0 ? Wg : m == 1 ? Wu : Wd) + (size_t)e * (D_DIM * D_DIM);
  else           src = (m == 0 ? sg : m == 1 ? su : sd);

  __shared__ float tile[64][65];   // +1 pad: conflict-free column reads
  int tid = threadIdx.x;
#pragma unroll
  for (int it = 0; it < 4; it++) {
    int flat = it * 1024 + tid * 4;
    int r = flat >> 6, c = flat & 63;
    float4 v = *(const float4*)&src[(size_t)(kt + r) * D_DIM + nt + c];
    tile[r][c] = v.x; tile[r][c + 1] = v.y; tile[r][c + 2] = v.z; tile[r][c + 3] = v.w;
  }
  __syncthreads();
#pragma unroll
  for (int it = 0; it < 2; it++) {
    int flat = it * 2048 + tid * 8;   // element index in 64x64 tile, [n][k] order
    int nl = flat >> 6, kl = flat & 63;
    int n = nt + nl, k = kt + kl;
    u16x8 o;
#pragma unroll
    for (int j = 0; j < 8; j++) o[j] = f2b(tile[kl + j][nl]);
    unsigned short* dst;
    if (m < 2) {
      int prow = ((n >> 4) * 32) + m * 16 + (n & 15);
      dst = Wt1 + (size_t)e * (2048 * 1024) + (size_t)prow * D_DIM + k;
    } else {
      dst = Wt2 + (size_t)e * (1024 * 1024) + (size_t)n * D_DIM + k;
    }
    *(u16x8*)dst = o;
  }
}

// ---------------- routing dispatch (1 block) ----------------
__global__ void k_dispatch(const int* __restrict__ idx,
                           int* __restrict__ etok, int* __restrict__ pos2,
                           int* __restrict__ ebase, int* __restrict__ tile_e,
                           int* __restrict__ tile_r, int* __restrict__ ntp) {
  __shared__ int cnt[ESLOT];
  __shared__ int cur[E_NUM];
  __shared__ int basz[ESLOT + 1];
  int tid = threadIdx.x;  // 256
  if (tid < ESLOT) cnt[tid] = 0;
  __syncthreads();
  for (int i = tid; i < NROUTE; i += 256) atomicAdd(&cnt[idx[i]], 1);
  __syncthreads();
  if (tid == 0) {
    int off = 0;
    for (int e = 0; e < E_NUM; e++) { basz[e] = off; off += ((cnt[e] + BM - 1) / BM) * BM; }
    basz[E_NUM] = off;                 // shared expert segment (4096, already x128)
    basz[E_NUM + 1] = off + NTOK;
    int t = 0;
    for (int e = 0; e <= E_NUM; e++) {
      int c = (e == E_NUM) ? NTOK : cnt[e];
      for (int r = 0; r < c; r += BM) { tile_e[t] = e; tile_r[t] = basz[e] + r; t++; }
    }
    *ntp = t;                          // <= 112
  }
  if (tid < E_NUM) cur[tid] = 0;
  __syncthreads();
  for (int i = tid; i < NROUTE; i += 256) {
    int e = idx[i];
    int p = basz[e] + atomicAdd(&cur[e], 1);
    etok[p] = i >> 1;                  // token id (K=2)
    pos2[i] = p;                       // where (token,k)'s y lands
  }
  for (int i = tid; i < NTOK; i += 256) etok[basz[E_NUM] + i] = i;
  if (tid < ESLOT + 1) ebase[tid] = basz[tid];
}

// ---- grouped GEMM, 128x128 tile, 4 waves, 3-buffer pipeline, counted vmcnt ----
// LDS per buffer: A [kq][128][8] (8KB) then B [kq][128][8] (8KB).
// Schedule/iter: vmcnt(4) -> s_barrier -> STAGE(t+2) -> ds_read -> MFMA.
// Stage AFTER barrier => buf[(t+2)%3]'s previous readers (iter t-1) have
// consumed into regs before their barrier(t) arrival -> 3 buffers race-free.
template <bool GATHER, bool ACT>
__device__ __forceinline__ void gemm_body(
    const unsigned short* __restrict__ Abase, int lda,
    const unsigned short* __restrict__ Wslot, size_t slot_stride,
    const int* __restrict__ etok,
    const int* __restrict__ tile_e, const int* __restrict__ tile_r,
    const int* __restrict__ ntp,
    unsigned short* __restrict__ Out, int ldo) {
  int bt = blockIdx.y;
  if (bt >= *ntp) return;
  int e = tile_e[bt];
  int row0 = tile_r[bt];
  int n0 = blockIdx.x * BN;   // physical B-row (output col) base

  __shared__ __align__(16) char smem[3 * 16384];

  int tid = threadIdx.x;
  int wid = tid >> 6, lane = tid & 63;
  int wm = wid >> 1, wn = wid & 1;

  int srow = tid & 127;
  int kq0 = tid >> 7;    // 0/1; second instr covers kq0+2
  size_t arow = GATHER ? (size_t)etok[row0 + srow] : (size_t)(row0 + srow);
  const unsigned short* aptr = Abase + arow * (size_t)lda + kq0 * 8;
  const unsigned short* bptr = Wslot + (size_t)e * slot_stride
                               + (size_t)(n0 + srow) * D_DIM + kq0 * 8;

  int a_off[4], b_off[4];
#pragma unroll
  for (int f = 0; f < 4; f++) {
    a_off[f] = ((lane >> 4) * 128 + wm * 64 + f * 16 + (lane & 15)) * 16;
    b_off[f] = 8192 + ((lane >> 4) * 128 + wn * 64 + f * 16 + (lane & 15)) * 16;
  }

  f32x4 acc[4][4] = {};

#define STAGE(t, buf)                                         \
  do {                                                        \
    const unsigned short* a_ = aptr + (t) * 32;               \
    const unsigned short* b_ = bptr + (t) * 32;               \
    gload_lds16(a_,      (buf) + wid * 1024);                 \
    gload_lds16(a_ + 16, (buf) + 4096 + wid * 1024);          \
    gload_lds16(b_,      (buf) + 8192 + wid * 1024);          \
    gload_lds16(b_ + 16, (buf) + 12288 + wid * 1024);         \
  } while (0)

  STAGE(0, smem);
  STAGE(1, smem + 16384);

#pragma unroll
  for (int t = 0; t < NT; t++) {
    if (t < NT - 1) asm volatile("s_waitcnt vmcnt(4)" ::: "memory");
    else            asm volatile("s_waitcnt vmcnt(0)" ::: "memory");
    __builtin_amdgcn_s_barrier();
    __builtin_amdgcn_sched_barrier(0);
    if (t + 2 < NT) STAGE(t + 2, smem + ((t + 2) % 3) * 16384);
    char* cur = smem + (t % 3) * 16384;
    bf16x8 af[4], bfr[4];
#pragma unroll
    for (int f = 0; f < 4; f++) {
      af[f]  = *(const bf16x8*)(cur + a_off[f]);
      bfr[f] = *(const bf16x8*)(cur + b_off[f]);
    }
    __builtin_amdgcn_s_setprio(1);
#pragma unroll
    for (int i = 0; i < 4; i++)
#pragma unroll
      for (int j = 0; j < 4; j++)
        acc[i][j] = __builtin_amdgcn_mfma_f32_16x16x32_bf16(af[i], bfr[j], acc[i][j], 0, 0, 0);
    __builtin_amdgcn_s_setprio(0);
  }
#undef STAGE

  // C/D layout: col=lane&15, row=(lane>>4)*4+q (m89/m91 verified)
  int crow = row0 + wm * 64 + (lane >> 4) * 4;
  if constexpr (ACT) {
    // frag j=2a holds gate 16-col group a, j=2a+1 the matching up group.
    int ccol = blockIdx.x * 64 + wn * 32 + (lane & 15);
#pragma unroll
    for (int i = 0; i < 4; i++)
#pragma unroll
      for (int a = 0; a < 2; a++)
#pragma unroll
        for (int q = 0; q < 4; q++) {
          float g = acc[i][2 * a][q];
          float u = acc[i][2 * a + 1][q];
          float v = g / (1.f + __expf(-g)) * u;
          Out[(size_t)(crow + i * 16 + q) * ldo + ccol + a * 16] = f2b(v);
        }
  } else {
    int ccol = n0 + wn * 64 + (lane & 15);
#pragma unroll
    for (int i = 0; i < 4; i++)
#pragma unroll
      for (int j = 0; j < 4; j++)
#pragma unroll
        for (int q = 0; q < 4; q++)
          Out[(size_t)(crow + i * 16 + q) * ldo + ccol + j * 16] = f2b(acc[i][j][q]);
  }
}

__global__ void __launch_bounds__(256)
k_gemm_gu(const unsigned short* __restrict__ xb, const unsigned short* __restrict__ Wt1,
          const int* __restrict__ etok, const int* __restrict__ tile_e,
          const int* __restrict__ tile_r, const int* __restrict__ ntp,
          unsigned short* __restrict__ Aact) {
  gemm_body<true, true>(xb, 1024, Wt1, (size_t)2048 * 1024, etok, tile_e, tile_r, ntp,
                        Aact, 1024);
}

__global__ void __launch_bounds__(256)
k_gemm_dn(const unsigned short* __restrict__ Aact, const unsigned short* __restrict__ Wt2,
          const int* __restrict__ tile_e, const int* __restrict__ tile_r,
          const int* __restrict__ ntp, unsigned short* __restrict__ Y) {
  gemm_body<false, false>(Aact, 1024, Wt2, (size_t)1024 * 1024, nullptr, tile_e, tile_r, ntp,
                          Y, 1024);
}

// ---------------- combine: out = w0*Y[p0] + w1*Y[p1] + Y[shared] ----------------
__global__ void k_combine(const unsigned short* __restrict__ Y, const float* __restrict__ w,
                          const int* __restrict__ pos2, const int* __restrict__ ebase,
                          float* __restrict__ out) {
  int t = blockIdx.x;
  int tid = threadIdx.x;
  int p0 = pos2[t * 2], p1 = pos2[t * 2 + 1];
  float w0 = w[t * 2], w1 = w[t * 2 + 1];
  int ps = ebase[E_NUM] + t;
  int c = tid * 4;
  ushort4 ya = *(const ushort4*)(Y + (size_t)p0 * D_DIM + c);
  ushort4 yb = *(const ushort4*)(Y + (size_t)p1 * D_DIM + c);
  ushort4 ys = *(const ushort4*)(Y + (size_t)ps * D_DIM + c);
  float4 o;
  o.x = w0 * b2f(ya.x) + w1 * b2f(yb.x) + b2f(ys.x);
  o.y = w0 * b2f(ya.y) + w1 * b2f(yb.y) + b2f(ys.y);
  o.z = w0 * b2f(ya.z) + w1 * b2f(yb.z) + b2f(ys.z);
  o.w = w0 * b2f(ya.w) + w1 * b2f(yb.w) + b2f(ys.w);
  *(float4*)(out + (size_t)t * D_DIM + c) = o;
}

extern "C" void kernel_launch(void* const* d_in, const int* in_sizes, int n_in,
                              void* d_out, int out_size, void* d_ws, size_t ws_size,
                              hipStream_t stream) {
  (void)in_sizes; (void)n_in; (void)out_size; (void)ws_size;
  const float* x  = (const float*)d_in[0];
  const float* w  = (const float*)d_in[1];
  const int*   idx = (const int*)d_in[2];
  const float* Wg = (const float*)d_in[5];
  const float* Wu = (const float*)d_in[6];
  const float* Wd = (const float*)d_in[7];
  const float* sg = (const float*)d_in[8];
  const float* su = (const float*)d_in[9];
  const float* sd = (const float*)d_in[10];
  float* out = (float*)d_out;

  // workspace layout (bytes) -- total 174,155,012 (same as proven rounds 1-2)
  char* ws = (char*)d_ws;
  unsigned short* Wt1  = (unsigned short*)(ws + 0);            // 17*2048*1024*2 =  71,303,168
  unsigned short* Wt2  = (unsigned short*)(ws + 71303168);     // 17*1024*1024*2 =  35,651,584
  unsigned short* Aact = (unsigned short*)(ws + 106954752);    // 14336*1024*2   =  29,360,128
  unsigned short* Y    = (unsigned short*)(ws + 136314880);    // 14336*1024*2   =  29,360,128
  unsigned short* xb   = (unsigned short*)(ws + 165675008);    // 4096*1024*2    =   8,388,608
  int* etok   = (int*)(ws + 174063616);                        // 14336*4
  int* pos2   = (int*)(ws + 174120960);                        // 8192*4
  int* ebase  = (int*)(ws + 174153728);                        // 18*4 (pad 256)
  int* tile_e = (int*)(ws + 174153984);                        // 112*4 (pad 512)
  int* tile_r = (int*)(ws + 174154496);                        // 112*4 (pad 512)
  int* ntp    = (int*)(ws + 174155008);                        // 4

  k_convert_x<<<4096, 256, 0, stream>>>(x, xb, etok);
  k_trans_w<<<51 * 256, 256, 0, stream>>>(Wg, Wu, Wd, sg, su, sd, Wt1, Wt2);
  k_dispatch<<<1, 256, 0, stream>>>(idx, etok, pos2, ebase, tile_e, tile_r, ntp);
  k_gemm_gu<<<dim3(16, MAXTILES), 256, 0, stream>>>(xb, Wt1, etok, tile_e, tile_r, ntp, Aact);
  k_gemm_dn<<<dim3(8, MAXTILES), 256, 0, stream>>>(Aact, Wt2, tile_e, tile_r, ntp, Y);
  k_combine<<<NTOK, 256, 0, stream>>>(Y, w, pos2, ebase, out);
}